// Round 1
// baseline (1683.146 us; speedup 1.0000x reference)
//
#include <hip/hip_runtime.h>
#include <math.h>

#define N_NODES 50000
#define N_EDGES 800000
#define IN_C 16
#define HID_C 16
#define OUT_C 10
#define N_GRAPHS 500
#define EDGE_DIM 3
#define MLP_HID 25
#define BN_EPS 1e-5f

__device__ __forceinline__ void atomAdd(float* p, float v) {
    unsafeAtomicAdd(p, v);  // HW global_atomic_add_f32 on gfx90a+
}

__global__ __launch_bounds__(256) void zero_kernel(float* __restrict__ p, int n) {
    int i = blockIdx.x * blockDim.x + threadIdx.x;
    if (i < n) p[i] = 0.f;
}

// Fold BatchNorm(eval) into the first linear of the edge MLP:
// h[k] = relu(a0*A0[k] + a1*A1[k] + a2*A2[k] + C[k]), stored as [k][4] = {A0,A1,A2,C}
__global__ void prep_kernel(
    const float* __restrict__ W1a, const float* __restrict__ b1a,
    const float* __restrict__ g1, const float* __restrict__ bt1,
    const float* __restrict__ m1, const float* __restrict__ v1,
    const float* __restrict__ W2a, const float* __restrict__ b2a,
    const float* __restrict__ g2, const float* __restrict__ bt2,
    const float* __restrict__ m2, const float* __restrict__ v2,
    float* __restrict__ AC1, float* __restrict__ AC2)
{
    int t = threadIdx.x;
    if (t < MLP_HID) {
        int k = t;
        float sc = g1[k] / sqrtf(v1[k] + BN_EPS);
        AC1[k*4+0] = sc * W1a[0*MLP_HID+k];
        AC1[k*4+1] = sc * W1a[1*MLP_HID+k];
        AC1[k*4+2] = sc * W1a[2*MLP_HID+k];
        AC1[k*4+3] = sc * (b1a[k] - m1[k]) + bt1[k];
    } else if (t >= 32 && t < 32 + MLP_HID) {
        int k = t - 32;
        float sc = g2[k] / sqrtf(v2[k] + BN_EPS);
        AC2[k*4+0] = sc * W2a[0*MLP_HID+k];
        AC2[k*4+1] = sc * W2a[1*MLP_HID+k];
        AC2[k*4+2] = sc * W2a[2*MLP_HID+k];
        AC2[k*4+3] = sc * (b2a[k] - m2[k]) + bt2[k];
    }
}

__global__ __launch_bounds__(256) void deg_kernel(const int* __restrict__ dst,
                                                  float* __restrict__ deg) {
    int e = blockIdx.x * blockDim.x + threadIdx.x;
    if (e < N_EDGES) atomAdd(&deg[dst[e]], 1.f);
}

// Fused per-edge: edge-MLP (3->25->256), reshape to w[16][16], msg = x_src @ w,
// atomic scatter-add into agg[dst]. w is never materialized:
// msg[o] = sum_i xs[i]*bb[i*16+o] + sum_k h[k] * sum_i xs[i]*Wb[k][i*16+o]
__global__ __launch_bounds__(256) void edge_kernel(
    const float* __restrict__ xin,
    const int* __restrict__ src, const int* __restrict__ dst,
    const float* __restrict__ eattr,
    const float* __restrict__ AC,
    const float* __restrict__ Wb, const float* __restrict__ bb,
    float* __restrict__ agg)
{
    int e = blockIdx.x * blockDim.x + threadIdx.x;
    if (e >= N_EDGES) return;
    int s = src[e];
    int d = dst[e];
    float a0 = eattr[e*3+0];
    float a1 = eattr[e*3+1];
    float a2 = eattr[e*3+2];

    float xs[IN_C];
    {
        const float4* xp = (const float4*)(xin + (size_t)s * IN_C);
        float4 q0 = xp[0], q1 = xp[1], q2 = xp[2], q3 = xp[3];
        xs[0]=q0.x; xs[1]=q0.y; xs[2]=q0.z; xs[3]=q0.w;
        xs[4]=q1.x; xs[5]=q1.y; xs[6]=q1.z; xs[7]=q1.w;
        xs[8]=q2.x; xs[9]=q2.y; xs[10]=q2.z; xs[11]=q2.w;
        xs[12]=q3.x; xs[13]=q3.y; xs[14]=q3.z; xs[15]=q3.w;
    }

    float msg[HID_C];
    #pragma unroll
    for (int o = 0; o < HID_C; ++o) msg[o] = 0.f;

    // bias of the second linear (part of w)
    #pragma unroll
    for (int i = 0; i < IN_C; ++i) {
        #pragma unroll
        for (int o = 0; o < HID_C; ++o)
            msg[o] = fmaf(xs[i], bb[i*HID_C+o], msg[o]);
    }

    // main contraction; k kept as a real loop (I$-friendly), h recomputed per k
    // (4 VALU ops) to avoid dynamic register-array indexing. All Wb/AC accesses
    // are wave-uniform -> scalar loads through K$.
    #pragma unroll 1
    for (int k = 0; k < MLP_HID; ++k) {
        float A0 = AC[k*4+0], A1 = AC[k*4+1], A2 = AC[k*4+2], C = AC[k*4+3];
        float hk = fmaxf(fmaf(a2, A2, fmaf(a1, A1, fmaf(a0, A0, C))), 0.f);
        const float* Wrow = Wb + k * (IN_C*HID_C);
        #pragma unroll
        for (int i = 0; i < IN_C; ++i) {
            float ai = hk * xs[i];
            #pragma unroll
            for (int o = 0; o < HID_C; ++o)
                msg[o] = fmaf(ai, Wrow[i*HID_C+o], msg[o]);
        }
    }

    float* ap = agg + (size_t)d * HID_C;
    #pragma unroll
    for (int o = 0; o < HID_C; ++o) atomAdd(ap + o, msg[o]);
}

// x_out[n][o] = elu(agg[n][o]/max(deg,1) + sum_i x[n][i]*root[i][o] + bias[o])
__global__ __launch_bounds__(256) void node_kernel(
    const float* __restrict__ xin, const float* __restrict__ agg,
    const float* __restrict__ deg, const float* __restrict__ root,
    const float* __restrict__ bias, float* __restrict__ xout)
{
    int n = blockIdx.x * blockDim.x + threadIdx.x;
    if (n >= N_NODES) return;
    float inv = 1.f / fmaxf(deg[n], 1.f);

    float xs[IN_C];
    {
        const float4* xp = (const float4*)(xin + (size_t)n * IN_C);
        float4 q0 = xp[0], q1 = xp[1], q2 = xp[2], q3 = xp[3];
        xs[0]=q0.x; xs[1]=q0.y; xs[2]=q0.z; xs[3]=q0.w;
        xs[4]=q1.x; xs[5]=q1.y; xs[6]=q1.z; xs[7]=q1.w;
        xs[8]=q2.x; xs[9]=q2.y; xs[10]=q2.z; xs[11]=q2.w;
        xs[12]=q3.x; xs[13]=q3.y; xs[14]=q3.z; xs[15]=q3.w;
    }
    float acc[HID_C];
    #pragma unroll
    for (int o = 0; o < HID_C; ++o)
        acc[o] = fmaf(agg[(size_t)n*HID_C + o], inv, bias[o]);
    #pragma unroll
    for (int i = 0; i < IN_C; ++i) {
        #pragma unroll
        for (int o = 0; o < HID_C; ++o)
            acc[o] = fmaf(xs[i], root[i*HID_C+o], acc[o]);
    }
    #pragma unroll
    for (int o = 0; o < HID_C; ++o) {
        float val = acc[o];
        xout[(size_t)n*HID_C + o] = val > 0.f ? val : (expf(val) - 1.f);
    }
}

__global__ __launch_bounds__(256) void pool_kernel(
    const float* __restrict__ xin, const int* __restrict__ batch,
    float* __restrict__ pooled, float* __restrict__ cnt)
{
    int n = blockIdx.x * blockDim.x + threadIdx.x;
    if (n >= N_NODES) return;
    int g = batch[n];
    #pragma unroll
    for (int c = 0; c < HID_C; ++c)
        atomAdd(&pooled[(size_t)g*HID_C + c], xin[(size_t)n*HID_C + c]);
    atomAdd(&cnt[g], 1.f);
}

__global__ __launch_bounds__(256) void final_kernel(
    const float* __restrict__ pooled, const float* __restrict__ cnt,
    const float* __restrict__ fcW, const float* __restrict__ fcb,
    float* __restrict__ out)
{
    int idx = blockIdx.x * blockDim.x + threadIdx.x;
    if (idx >= N_GRAPHS * OUT_C) return;
    int g = idx / OUT_C, j = idx % OUT_C;
    float ic = 1.f / fmaxf(cnt[g], 1.f);
    float acc = fcb[j];
    #pragma unroll
    for (int i = 0; i < HID_C; ++i)
        acc = fmaf(pooled[(size_t)g*HID_C + i] * ic, fcW[i*OUT_C+j], acc);
    out[idx] = acc;
}

extern "C" void kernel_launch(void* const* d_in, const int* in_sizes, int n_in,
                              void* d_out, int out_size, void* d_ws, size_t ws_size,
                              hipStream_t stream)
{
    const float* x     = (const float*)d_in[0];
    const int*   ei    = (const int*)d_in[1];
    const float* eattr = (const float*)d_in[2];
    const int*   batch = (const int*)d_in[3];
    const float* W1a   = (const float*)d_in[4];
    const float* b1a   = (const float*)d_in[5];
    const float* g1    = (const float*)d_in[6];
    const float* bt1   = (const float*)d_in[7];
    const float* m1    = (const float*)d_in[8];
    const float* v1    = (const float*)d_in[9];
    const float* W1b   = (const float*)d_in[10];
    const float* b1b   = (const float*)d_in[11];
    const float* root1 = (const float*)d_in[12];
    const float* bias1 = (const float*)d_in[13];
    const float* W2a   = (const float*)d_in[14];
    const float* b2a   = (const float*)d_in[15];
    const float* g2    = (const float*)d_in[16];
    const float* bt2   = (const float*)d_in[17];
    const float* m2    = (const float*)d_in[18];
    const float* v2    = (const float*)d_in[19];
    const float* W2b   = (const float*)d_in[20];
    const float* b2b   = (const float*)d_in[21];
    const float* root2 = (const float*)d_in[22];
    const float* bias2 = (const float*)d_in[23];
    const float* fcW   = (const float*)d_in[24];
    const float* fcb   = (const float*)d_in[25];

    float* ws    = (float*)d_ws;
    float* agg   = ws;                 // 800000
    float* x1    = ws + 800000;        // 800000
    float* x2    = ws + 1600000;       // 800000
    float* deg   = ws + 2400000;       // 50000
    float* pooled= ws + 2450000;       // 8000
    float* cnt   = ws + 2458000;       // 500
    float* AC1   = ws + 2458512;       // 100 (16B aligned)
    float* AC2   = ws + 2458512 + 128; // 100

    const int* src = ei;
    const int* dst = ei + N_EDGES;

    // zero accumulators (ws is poisoned with 0xAA before every call)
    zero_kernel<<<(800000+255)/256, 256, 0, stream>>>(agg, 800000);
    zero_kernel<<<(58500+255)/256, 256, 0, stream>>>(deg, 58500); // deg+pooled+cnt contiguous
    prep_kernel<<<1, 64, 0, stream>>>(W1a, b1a, g1, bt1, m1, v1,
                                      W2a, b2a, g2, bt2, m2, v2, AC1, AC2);
    deg_kernel<<<N_EDGES/256, 256, 0, stream>>>(dst, deg);

    edge_kernel<<<N_EDGES/256, 256, 0, stream>>>(x, src, dst, eattr, AC1, W1b, b1b, agg);
    node_kernel<<<(N_NODES+255)/256, 256, 0, stream>>>(x, agg, deg, root1, bias1, x1);

    zero_kernel<<<(800000+255)/256, 256, 0, stream>>>(agg, 800000);
    edge_kernel<<<N_EDGES/256, 256, 0, stream>>>(x1, src, dst, eattr, AC2, W2b, b2b, agg);
    node_kernel<<<(N_NODES+255)/256, 256, 0, stream>>>(x1, agg, deg, root2, bias2, x2);

    pool_kernel<<<(N_NODES+255)/256, 256, 0, stream>>>(x2, batch, pooled, cnt);
    final_kernel<<<(N_GRAPHS*OUT_C+255)/256, 256, 0, stream>>>(pooled, cnt, fcW, fcb, (float*)d_out);
}

// Round 2
// 589.995 us; speedup vs baseline: 2.8528x; 2.8528x over previous
//
#include <hip/hip_runtime.h>
#include <math.h>

#define N_NODES 50000
#define N_EDGES 800000
#define IN_C 16
#define HID_C 16
#define OUT_C 10
#define N_GRAPHS 500
#define EDGE_DIM 3
#define MLP_HID 25
#define BN_EPS 1e-5f

__device__ __forceinline__ void atomAddF(float* p, float v) {
    unsafeAtomicAdd(p, v);  // HW global_atomic_add_f32
}

__global__ __launch_bounds__(256) void zero_f(float* __restrict__ p, int n) {
    int i = blockIdx.x * blockDim.x + threadIdx.x;
    if (i < n) p[i] = 0.f;
}
__global__ __launch_bounds__(256) void zero_i(int* __restrict__ p, int n) {
    int i = blockIdx.x * blockDim.x + threadIdx.x;
    if (i < n) p[i] = 0;
}

// Fold BatchNorm(eval) into the first linear of the edge MLP:
// h[k] = relu(a0*A0[k] + a1*A1[k] + a2*A2[k] + C[k]); AC[k][4] = {A0,A1,A2,C}
__global__ void prep_kernel(
    const float* __restrict__ W1a, const float* __restrict__ b1a,
    const float* __restrict__ g1, const float* __restrict__ bt1,
    const float* __restrict__ m1, const float* __restrict__ v1,
    const float* __restrict__ W2a, const float* __restrict__ b2a,
    const float* __restrict__ g2, const float* __restrict__ bt2,
    const float* __restrict__ m2, const float* __restrict__ v2,
    float* __restrict__ AC1, float* __restrict__ AC2)
{
    int t = threadIdx.x;
    if (t < MLP_HID) {
        int k = t;
        float sc = g1[k] / sqrtf(v1[k] + BN_EPS);
        AC1[k*4+0] = sc * W1a[0*MLP_HID+k];
        AC1[k*4+1] = sc * W1a[1*MLP_HID+k];
        AC1[k*4+2] = sc * W1a[2*MLP_HID+k];
        AC1[k*4+3] = sc * (b1a[k] - m1[k]) + bt1[k];
    } else if (t >= 32 && t < 32 + MLP_HID) {
        int k = t - 32;
        float sc = g2[k] / sqrtf(v2[k] + BN_EPS);
        AC2[k*4+0] = sc * W2a[0*MLP_HID+k];
        AC2[k*4+1] = sc * W2a[1*MLP_HID+k];
        AC2[k*4+2] = sc * W2a[2*MLP_HID+k];
        AC2[k*4+3] = sc * (b2a[k] - m2[k]) + bt2[k];
    }
}

// ---------------- CSR build ----------------

__global__ __launch_bounds__(256) void hist_kernel(const int* __restrict__ dst,
                                                   int* __restrict__ deg) {
    int e = blockIdx.x * blockDim.x + threadIdx.x;
    if (e < N_EDGES) atomicAdd(&deg[dst[e]], 1);
}

// single block of 1024: exclusive scan of deg -> off[0..N], cursor = off copy
__global__ __launch_bounds__(1024) void scan_kernel(const int* __restrict__ deg,
                                                    int* __restrict__ off,
                                                    int* __restrict__ cursor) {
    __shared__ int lds[1024];
    const int t = threadIdx.x;
    const int CHUNK = (N_NODES + 1023) / 1024;  // 49
    int lo = t * CHUNK;
    int hi = lo + CHUNK; if (hi > N_NODES) hi = N_NODES;
    int s = 0;
    for (int r = lo; r < hi; ++r) s += deg[r];
    lds[t] = s;
    __syncthreads();
    // Hillis-Steele inclusive scan over 1024 partials
    for (int d = 1; d < 1024; d <<= 1) {
        int v = (t >= d) ? lds[t - d] : 0;
        __syncthreads();
        lds[t] += v;
        __syncthreads();
    }
    int run = (t > 0) ? lds[t - 1] : 0;
    for (int r = lo; r < hi; ++r) {
        off[r] = run; cursor[r] = run;
        run += deg[r];
    }
    if (t == 1023) off[N_NODES] = lds[1023];
}

// pos[e] = CSR slot of edge e (rank within its dst bucket)
__global__ __launch_bounds__(256) void pos_kernel(const int* __restrict__ dst,
                                                  int* __restrict__ cursor,
                                                  int* __restrict__ pos) {
    int e = blockIdx.x * blockDim.x + threadIdx.x;
    if (e < N_EDGES) pos[e] = atomicAdd(&cursor[dst[e]], 1);
}

// goff[g] = first node index with batch >= g (batch is sorted)
__global__ __launch_bounds__(256) void graphoff_kernel(const int* __restrict__ batch,
                                                       int* __restrict__ goff) {
    int g = blockIdx.x * blockDim.x + threadIdx.x;
    if (g > N_GRAPHS) return;
    int lo = 0, hi = N_NODES;
    while (lo < hi) {
        int mid = (lo + hi) >> 1;
        if (batch[mid] < g) lo = mid + 1; else hi = mid;
    }
    goff[g] = lo;
}

// ---------------- hot path ----------------

// Fused per-edge: edge-MLP (3->25->256) x message contraction, NO atomics:
// writes msg row to CSR slot pos[e] with four float4 stores.
__global__ __launch_bounds__(256) void edge_kernel_pos(
    const float* __restrict__ xin,
    const int* __restrict__ src,
    const int* __restrict__ pos,
    const float* __restrict__ eattr,
    const float* __restrict__ AC,
    const float* __restrict__ Wb, const float* __restrict__ bb,
    float* __restrict__ msg_buf)
{
    int e = blockIdx.x * blockDim.x + threadIdx.x;
    if (e >= N_EDGES) return;
    int s = src[e];
    int p = pos[e];
    float a0 = eattr[e*3+0];
    float a1 = eattr[e*3+1];
    float a2 = eattr[e*3+2];

    float xs[IN_C];
    {
        const float4* xp = (const float4*)(xin + (size_t)s * IN_C);
        float4 q0 = xp[0], q1 = xp[1], q2 = xp[2], q3 = xp[3];
        xs[0]=q0.x; xs[1]=q0.y; xs[2]=q0.z; xs[3]=q0.w;
        xs[4]=q1.x; xs[5]=q1.y; xs[6]=q1.z; xs[7]=q1.w;
        xs[8]=q2.x; xs[9]=q2.y; xs[10]=q2.z; xs[11]=q2.w;
        xs[12]=q3.x; xs[13]=q3.y; xs[14]=q3.z; xs[15]=q3.w;
    }

    float msg[HID_C];
    #pragma unroll
    for (int o = 0; o < HID_C; ++o) msg[o] = 0.f;

    #pragma unroll
    for (int i = 0; i < IN_C; ++i) {
        #pragma unroll
        for (int o = 0; o < HID_C; ++o)
            msg[o] = fmaf(xs[i], bb[i*HID_C+o], msg[o]);
    }

    // wave-uniform Wb/AC accesses -> scalar loads through K$
    #pragma unroll 1
    for (int k = 0; k < MLP_HID; ++k) {
        float A0 = AC[k*4+0], A1 = AC[k*4+1], A2 = AC[k*4+2], C = AC[k*4+3];
        float hk = fmaxf(fmaf(a2, A2, fmaf(a1, A1, fmaf(a0, A0, C))), 0.f);
        const float* Wrow = Wb + k * (IN_C*HID_C);
        #pragma unroll
        for (int i = 0; i < IN_C; ++i) {
            float ai = hk * xs[i];
            #pragma unroll
            for (int o = 0; o < HID_C; ++o)
                msg[o] = fmaf(ai, Wrow[i*HID_C+o], msg[o]);
        }
    }

    float4* mp = (float4*)(msg_buf + (size_t)p * HID_C);
    mp[0] = make_float4(msg[0], msg[1], msg[2], msg[3]);
    mp[1] = make_float4(msg[4], msg[5], msg[6], msg[7]);
    mp[2] = make_float4(msg[8], msg[9], msg[10], msg[11]);
    mp[3] = make_float4(msg[12], msg[13], msg[14], msg[15]);
}

// 16 threads per node (lane = out channel). Segment-sum msg_buf rows
// [off[n], off[n+1]) -> mean -> + x@root + bias -> ELU.
__global__ __launch_bounds__(256) void node_gather_kernel(
    const float* __restrict__ xin, const float* __restrict__ msg_buf,
    const int* __restrict__ off,
    const float* __restrict__ root, const float* __restrict__ bias,
    float* __restrict__ xout)
{
    int t = blockIdx.x * blockDim.x + threadIdx.x;
    int n = t >> 4;
    int o = t & 15;
    if (n >= N_NODES) return;
    int lo = off[n], hi = off[n+1];
    float inv = 1.f / fmaxf((float)(hi - lo), 1.f);

    float s = 0.f;
    for (int r = lo; r < hi; ++r)
        s += msg_buf[(size_t)r * HID_C + o];

    float acc = fmaf(s, inv, bias[o]);
    const float* xr = xin + (size_t)n * IN_C;
    #pragma unroll
    for (int i = 0; i < IN_C; ++i)
        acc = fmaf(xr[i], root[i*HID_C+o], acc);
    xout[(size_t)n*HID_C + o] = acc > 0.f ? acc : (expf(acc) - 1.f);
}

// pooled[g][c] = mean over nodes of graph g (batch sorted -> contiguous)
__global__ __launch_bounds__(256) void pool_seg_kernel(
    const float* __restrict__ xin, const int* __restrict__ goff,
    float* __restrict__ pooled)
{
    int idx = blockIdx.x * blockDim.x + threadIdx.x;
    if (idx >= N_GRAPHS * HID_C) return;
    int g = idx >> 4, c = idx & 15;
    int lo = goff[g], hi = goff[g+1];
    float s = 0.f;
    for (int n = lo; n < hi; ++n)
        s += xin[(size_t)n*HID_C + c];
    pooled[idx] = s / fmaxf((float)(hi - lo), 1.f);
}

__global__ __launch_bounds__(256) void final_kernel(
    const float* __restrict__ pooled,
    const float* __restrict__ fcW, const float* __restrict__ fcb,
    float* __restrict__ out)
{
    int idx = blockIdx.x * blockDim.x + threadIdx.x;
    if (idx >= N_GRAPHS * OUT_C) return;
    int g = idx / OUT_C, j = idx % OUT_C;
    float acc = fcb[j];
    #pragma unroll
    for (int i = 0; i < HID_C; ++i)
        acc = fmaf(pooled[g*HID_C + i], fcW[i*OUT_C+j], acc);
    out[idx] = acc;
}

// ---------------- fallback (atomic) path, used only if ws too small ----------

__global__ __launch_bounds__(256) void deg_kernel_f(const int* __restrict__ dst,
                                                    float* __restrict__ deg) {
    int e = blockIdx.x * blockDim.x + threadIdx.x;
    if (e < N_EDGES) atomAddF(&deg[dst[e]], 1.f);
}

__global__ __launch_bounds__(256) void edge_kernel_atomic(
    const float* __restrict__ xin,
    const int* __restrict__ src, const int* __restrict__ dst,
    const float* __restrict__ eattr,
    const float* __restrict__ AC,
    const float* __restrict__ Wb, const float* __restrict__ bb,
    float* __restrict__ agg)
{
    int e = blockIdx.x * blockDim.x + threadIdx.x;
    if (e >= N_EDGES) return;
    int s = src[e];
    int d = dst[e];
    float a0 = eattr[e*3+0], a1 = eattr[e*3+1], a2 = eattr[e*3+2];
    float xs[IN_C];
    {
        const float4* xp = (const float4*)(xin + (size_t)s * IN_C);
        float4 q0 = xp[0], q1 = xp[1], q2 = xp[2], q3 = xp[3];
        xs[0]=q0.x; xs[1]=q0.y; xs[2]=q0.z; xs[3]=q0.w;
        xs[4]=q1.x; xs[5]=q1.y; xs[6]=q1.z; xs[7]=q1.w;
        xs[8]=q2.x; xs[9]=q2.y; xs[10]=q2.z; xs[11]=q2.w;
        xs[12]=q3.x; xs[13]=q3.y; xs[14]=q3.z; xs[15]=q3.w;
    }
    float msg[HID_C];
    #pragma unroll
    for (int o = 0; o < HID_C; ++o) msg[o] = 0.f;
    #pragma unroll
    for (int i = 0; i < IN_C; ++i)
        #pragma unroll
        for (int o = 0; o < HID_C; ++o)
            msg[o] = fmaf(xs[i], bb[i*HID_C+o], msg[o]);
    #pragma unroll 1
    for (int k = 0; k < MLP_HID; ++k) {
        float A0 = AC[k*4+0], A1 = AC[k*4+1], A2 = AC[k*4+2], C = AC[k*4+3];
        float hk = fmaxf(fmaf(a2, A2, fmaf(a1, A1, fmaf(a0, A0, C))), 0.f);
        const float* Wrow = Wb + k * (IN_C*HID_C);
        #pragma unroll
        for (int i = 0; i < IN_C; ++i) {
            float ai = hk * xs[i];
            #pragma unroll
            for (int o = 0; o < HID_C; ++o)
                msg[o] = fmaf(ai, Wrow[i*HID_C+o], msg[o]);
        }
    }
    float* ap = agg + (size_t)d * HID_C;
    #pragma unroll
    for (int o = 0; o < HID_C; ++o) atomAddF(ap + o, msg[o]);
}

__global__ __launch_bounds__(256) void node_kernel_agg(
    const float* __restrict__ xin, const float* __restrict__ agg,
    const float* __restrict__ deg, const float* __restrict__ root,
    const float* __restrict__ bias, float* __restrict__ xout)
{
    int t = blockIdx.x * blockDim.x + threadIdx.x;
    int n = t >> 4, o = t & 15;
    if (n >= N_NODES) return;
    float inv = 1.f / fmaxf(deg[n], 1.f);
    float acc = fmaf(agg[(size_t)n*HID_C + o], inv, bias[o]);
    const float* xr = xin + (size_t)n * IN_C;
    #pragma unroll
    for (int i = 0; i < IN_C; ++i)
        acc = fmaf(xr[i], root[i*HID_C+o], acc);
    xout[(size_t)n*HID_C + o] = acc > 0.f ? acc : (expf(acc) - 1.f);
}

// ---------------- launch ----------------

extern "C" void kernel_launch(void* const* d_in, const int* in_sizes, int n_in,
                              void* d_out, int out_size, void* d_ws, size_t ws_size,
                              hipStream_t stream)
{
    const float* x     = (const float*)d_in[0];
    const int*   ei    = (const int*)d_in[1];
    const float* eattr = (const float*)d_in[2];
    const int*   batch = (const int*)d_in[3];
    const float* W1a   = (const float*)d_in[4];
    const float* b1a   = (const float*)d_in[5];
    const float* g1    = (const float*)d_in[6];
    const float* bt1   = (const float*)d_in[7];
    const float* m1    = (const float*)d_in[8];
    const float* v1    = (const float*)d_in[9];
    const float* W1b   = (const float*)d_in[10];
    const float* b1b   = (const float*)d_in[11];
    const float* root1 = (const float*)d_in[12];
    const float* bias1 = (const float*)d_in[13];
    const float* W2a   = (const float*)d_in[14];
    const float* b2a   = (const float*)d_in[15];
    const float* g2    = (const float*)d_in[16];
    const float* bt2   = (const float*)d_in[17];
    const float* m2    = (const float*)d_in[18];
    const float* v2    = (const float*)d_in[19];
    const float* W2b   = (const float*)d_in[20];
    const float* b2b   = (const float*)d_in[21];
    const float* root2 = (const float*)d_in[22];
    const float* bias2 = (const float*)d_in[23];
    const float* fcW   = (const float*)d_in[24];
    const float* fcb   = (const float*)d_in[25];

    const int* src = ei;
    const int* dst = ei + N_EDGES;

    const size_t NEED = (size_t)15358784 * 4;  // ~61.4 MB

    if (ws_size >= NEED) {
        float* ws   = (float*)d_ws;
        float* MSG  = ws;                         // 12,800,000
        float* X1   = ws + 12800000;              // 800,000
        float* X2   = ws + 13600000;              // 800,000
        int*   POS  = (int*)(ws + 14400000);      // 800,000
        int*   DEGI = (int*)(ws + 15200000);      // 50,000
        int*   OFF  = (int*)(ws + 15250000);      // 50,001 (+pad)
        int*   CUR  = (int*)(ws + 15300016);      // 50,000
        int*   GOFF = (int*)(ws + 15350016);      // 501 (+pad)
        float* POOL = ws + 15350528;              // 8,000
        float* AC1  = ws + 15358528;              // 128
        float* AC2  = ws + 15358656;              // 128

        zero_i<<<(N_NODES+255)/256, 256, 0, stream>>>(DEGI, N_NODES);
        prep_kernel<<<1, 64, 0, stream>>>(W1a, b1a, g1, bt1, m1, v1,
                                          W2a, b2a, g2, bt2, m2, v2, AC1, AC2);
        hist_kernel<<<N_EDGES/256, 256, 0, stream>>>(dst, DEGI);
        scan_kernel<<<1, 1024, 0, stream>>>(DEGI, OFF, CUR);
        pos_kernel<<<N_EDGES/256, 256, 0, stream>>>(dst, CUR, POS);
        graphoff_kernel<<<3, 256, 0, stream>>>(batch, GOFF);

        edge_kernel_pos<<<N_EDGES/256, 256, 0, stream>>>(x, src, POS, eattr, AC1, W1b, b1b, MSG);
        node_gather_kernel<<<(N_NODES*16+255)/256, 256, 0, stream>>>(x, MSG, OFF, root1, bias1, X1);

        edge_kernel_pos<<<N_EDGES/256, 256, 0, stream>>>(X1, src, POS, eattr, AC2, W2b, b2b, MSG);
        node_gather_kernel<<<(N_NODES*16+255)/256, 256, 0, stream>>>(X1, MSG, OFF, root2, bias2, X2);

        pool_seg_kernel<<<(N_GRAPHS*HID_C+255)/256, 256, 0, stream>>>(X2, GOFF, POOL);
        final_kernel<<<(N_GRAPHS*OUT_C+255)/256, 256, 0, stream>>>(POOL, fcW, fcb, (float*)d_out);
    } else {
        // fallback: R1 atomic path (ws too small for CSR + msg buffer)
        float* ws   = (float*)d_ws;
        float* AGG  = ws;                  // 800,000
        float* X1   = ws + 800000;
        float* X2   = ws + 1600000;
        float* DEGF = ws + 2400000;        // 50,000
        int*   GOFF = (int*)(ws + 2450000);// 501
        float* POOL = ws + 2450512;        // 8,000
        float* AC1  = ws + 2458512;
        float* AC2  = ws + 2458640;

        zero_f<<<(800000+255)/256, 256, 0, stream>>>(AGG, 800000);
        zero_f<<<(50000+255)/256, 256, 0, stream>>>(DEGF, 50000);
        prep_kernel<<<1, 64, 0, stream>>>(W1a, b1a, g1, bt1, m1, v1,
                                          W2a, b2a, g2, bt2, m2, v2, AC1, AC2);
        deg_kernel_f<<<N_EDGES/256, 256, 0, stream>>>(dst, DEGF);
        graphoff_kernel<<<3, 256, 0, stream>>>(batch, GOFF);

        edge_kernel_atomic<<<N_EDGES/256, 256, 0, stream>>>(x, src, dst, eattr, AC1, W1b, b1b, AGG);
        node_kernel_agg<<<(N_NODES*16+255)/256, 256, 0, stream>>>(x, AGG, DEGF, root1, bias1, X1);

        zero_f<<<(800000+255)/256, 256, 0, stream>>>(AGG, 800000);
        edge_kernel_atomic<<<N_EDGES/256, 256, 0, stream>>>(X1, src, dst, eattr, AC2, W2b, b2b, AGG);
        node_kernel_agg<<<(N_NODES*16+255)/256, 256, 0, stream>>>(X1, AGG, DEGF, root2, bias2, X2);

        pool_seg_kernel<<<(N_GRAPHS*HID_C+255)/256, 256, 0, stream>>>(X2, GOFF, POOL);
        final_kernel<<<(N_GRAPHS*OUT_C+255)/256, 256, 0, stream>>>(POOL, fcW, fcb, (float*)d_out);
    }
}

// Round 4
// 581.970 us; speedup vs baseline: 2.8922x; 1.0138x over previous
//
#include <hip/hip_runtime.h>
#include <math.h>

#define N_NODES 50000
#define N_EDGES 800000
#define IN_C 16
#define HID_C 16
#define OUT_C 10
#define N_GRAPHS 500
#define EDGE_DIM 3
#define MLP_HID 25
#define BN_EPS 1e-5f

// ---------------- small prep ----------------

// block 0: fold BN into edge-MLP layer-1 -> AC[k][4]={A0,A1,A2,C}
// all blocks: goff[g] = lower_bound(batch, g) (batch sorted)
__global__ __launch_bounds__(256) void prep_graph_kernel(
    const float* __restrict__ W1a, const float* __restrict__ b1a,
    const float* __restrict__ g1, const float* __restrict__ bt1,
    const float* __restrict__ m1, const float* __restrict__ v1,
    const float* __restrict__ W2a, const float* __restrict__ b2a,
    const float* __restrict__ g2, const float* __restrict__ bt2,
    const float* __restrict__ m2, const float* __restrict__ v2,
    const int* __restrict__ batch,
    float* __restrict__ AC1, float* __restrict__ AC2,
    int* __restrict__ goff)
{
    int t = threadIdx.x;
    if (blockIdx.x == 0) {
        if (t < MLP_HID) {
            int k = t;
            float sc = g1[k] / sqrtf(v1[k] + BN_EPS);
            AC1[k*4+0] = sc * W1a[0*MLP_HID+k];
            AC1[k*4+1] = sc * W1a[1*MLP_HID+k];
            AC1[k*4+2] = sc * W1a[2*MLP_HID+k];
            AC1[k*4+3] = sc * (b1a[k] - m1[k]) + bt1[k];
        } else if (t >= 32 && t < 32 + MLP_HID) {
            int k = t - 32;
            float sc = g2[k] / sqrtf(v2[k] + BN_EPS);
            AC2[k*4+0] = sc * W2a[0*MLP_HID+k];
            AC2[k*4+1] = sc * W2a[1*MLP_HID+k];
            AC2[k*4+2] = sc * W2a[2*MLP_HID+k];
            AC2[k*4+3] = sc * (b2a[k] - m2[k]) + bt2[k];
        }
    }
    int g = blockIdx.x * blockDim.x + t;
    if (g <= N_GRAPHS) {
        int lo = 0, hi = N_NODES;
        while (lo < hi) {
            int mid = (lo + hi) >> 1;
            if (batch[mid] < g) lo = mid + 1; else hi = mid;
        }
        goff[g] = lo;
    }
}

// ---------------- CSR build ----------------

__global__ __launch_bounds__(256) void hist_kernel(const int* __restrict__ dst,
                                                   int* __restrict__ deg) {
    int e = blockIdx.x * blockDim.x + threadIdx.x;
    if (e < N_EDGES) atomicAdd(&deg[dst[e]], 1);
}

// single block of 1024: exclusive scan of deg -> off[0..N]; also pre-seed the
// two per-layer cursor arrays (stride-4 ints = 16B apart, cuts cacheline
// serialization of the in-edge-kernel atomics 4x).
__global__ __launch_bounds__(1024) void scan_kernel(const int* __restrict__ deg,
                                                    int* __restrict__ off,
                                                    int* __restrict__ cur1,
                                                    int* __restrict__ cur2) {
    __shared__ int lds[1024];
    const int t = threadIdx.x;
    const int CHUNK = (N_NODES + 1023) / 1024;  // 49
    int lo = t * CHUNK;
    int hi = lo + CHUNK; if (hi > N_NODES) hi = N_NODES;
    int s = 0;
    for (int r = lo; r < hi; ++r) s += deg[r];
    lds[t] = s;
    __syncthreads();
    for (int d = 1; d < 1024; d <<= 1) {
        int v = (t >= d) ? lds[t - d] : 0;
        __syncthreads();
        lds[t] += v;
        __syncthreads();
    }
    int run = (t > 0) ? lds[t - 1] : 0;
    for (int r = lo; r < hi; ++r) {
        off[r] = run;
        cur1[r*4] = run;
        cur2[r*4] = run;
        run += deg[r];
    }
    if (t == 1023) off[N_NODES] = lds[1023];
}

// ---------------- hot path ----------------

// Fused per-edge: edge-MLP (3->25->256) x message contraction.
// 2 edges per thread (e, e+400000): both share the wave-uniform Wb scalar-load
// stream -> 2x FMA per s_load, 2x ILP. CSR slot claimed via early
// atomicAdd-with-return on pre-seeded cursors (latency hides under the FMA body).
__global__ __launch_bounds__(256) void edge_kernel2(
    const float* __restrict__ xin,
    const int* __restrict__ src, const int* __restrict__ dst,
    const float* __restrict__ eattr,
    int* __restrict__ cur,
    const float* __restrict__ AC,
    const float* __restrict__ Wb, const float* __restrict__ bb,
    float* __restrict__ msg_buf)
{
    const int HALF = N_EDGES / 2;
    int e = blockIdx.x * blockDim.x + threadIdx.x;
    if (e >= HALF) return;
    int eB = e + HALF;

    int sA = src[e],  sB = src[eB];
    int dA = dst[e],  dB = dst[eB];
    // claim CSR slots early; result needed only at the final store
    int pA = atomicAdd(&cur[dA*4], 1);
    int pB = atomicAdd(&cur[dB*4], 1);

    float aA0 = eattr[e*3+0],  aA1 = eattr[e*3+1],  aA2 = eattr[e*3+2];
    float aB0 = eattr[eB*3+0], aB1 = eattr[eB*3+1], aB2 = eattr[eB*3+2];

    float xsA[IN_C], xsB[IN_C];
    {
        const float4* xp = (const float4*)(xin + (size_t)sA * IN_C);
        float4 q0 = xp[0], q1 = xp[1], q2 = xp[2], q3 = xp[3];
        xsA[0]=q0.x; xsA[1]=q0.y; xsA[2]=q0.z; xsA[3]=q0.w;
        xsA[4]=q1.x; xsA[5]=q1.y; xsA[6]=q1.z; xsA[7]=q1.w;
        xsA[8]=q2.x; xsA[9]=q2.y; xsA[10]=q2.z; xsA[11]=q2.w;
        xsA[12]=q3.x; xsA[13]=q3.y; xsA[14]=q3.z; xsA[15]=q3.w;
    }
    {
        const float4* xp = (const float4*)(xin + (size_t)sB * IN_C);
        float4 q0 = xp[0], q1 = xp[1], q2 = xp[2], q3 = xp[3];
        xsB[0]=q0.x; xsB[1]=q0.y; xsB[2]=q0.z; xsB[3]=q0.w;
        xsB[4]=q1.x; xsB[5]=q1.y; xsB[6]=q1.z; xsB[7]=q1.w;
        xsB[8]=q2.x; xsB[9]=q2.y; xsB[10]=q2.z; xsB[11]=q2.w;
        xsB[12]=q3.x; xsB[13]=q3.y; xsB[14]=q3.z; xsB[15]=q3.w;
    }

    float msgA[HID_C], msgB[HID_C];
    #pragma unroll
    for (int o = 0; o < HID_C; ++o) { msgA[o] = 0.f; msgB[o] = 0.f; }

    // bias of the second linear (part of w)
    #pragma unroll
    for (int i = 0; i < IN_C; ++i) {
        #pragma unroll
        for (int o = 0; o < HID_C; ++o) {
            float w = bb[i*HID_C+o];
            msgA[o] = fmaf(xsA[i], w, msgA[o]);
            msgB[o] = fmaf(xsB[i], w, msgB[o]);
        }
    }

    #pragma unroll 1
    for (int k = 0; k < MLP_HID; ++k) {
        float A0 = AC[k*4+0], A1 = AC[k*4+1], A2 = AC[k*4+2], C = AC[k*4+3];
        float hA = fmaxf(fmaf(aA2, A2, fmaf(aA1, A1, fmaf(aA0, A0, C))), 0.f);
        float hB = fmaxf(fmaf(aB2, A2, fmaf(aB1, A1, fmaf(aB0, A0, C))), 0.f);
        const float* Wrow = Wb + k * (IN_C*HID_C);
        #pragma unroll
        for (int i = 0; i < IN_C; ++i) {
            float aiA = hA * xsA[i];
            float aiB = hB * xsB[i];
            #pragma unroll
            for (int o = 0; o < HID_C; ++o) {
                float w = Wrow[i*HID_C+o];
                msgA[o] = fmaf(aiA, w, msgA[o]);
                msgB[o] = fmaf(aiB, w, msgB[o]);
            }
        }
    }

    float4* mpA = (float4*)(msg_buf + (size_t)pA * HID_C);
    mpA[0] = make_float4(msgA[0], msgA[1], msgA[2], msgA[3]);
    mpA[1] = make_float4(msgA[4], msgA[5], msgA[6], msgA[7]);
    mpA[2] = make_float4(msgA[8], msgA[9], msgA[10], msgA[11]);
    mpA[3] = make_float4(msgA[12], msgA[13], msgA[14], msgA[15]);
    float4* mpB = (float4*)(msg_buf + (size_t)pB * HID_C);
    mpB[0] = make_float4(msgB[0], msgB[1], msgB[2], msgB[3]);
    mpB[1] = make_float4(msgB[4], msgB[5], msgB[6], msgB[7]);
    mpB[2] = make_float4(msgB[8], msgB[9], msgB[10], msgB[11]);
    mpB[3] = make_float4(msgB[12], msgB[13], msgB[14], msgB[15]);
}

// 16 threads per node (lane = out channel). Segment-sum msg_buf rows
// [off[n], off[n+1]) -> mean -> + x@root + bias -> ELU. 2 rows/iter for MLP.
__global__ __launch_bounds__(256) void node_gather_kernel(
    const float* __restrict__ xin, const float* __restrict__ msg_buf,
    const int* __restrict__ off,
    const float* __restrict__ root, const float* __restrict__ bias,
    float* __restrict__ xout)
{
    int t = blockIdx.x * blockDim.x + threadIdx.x;
    int n = t >> 4;
    int o = t & 15;
    if (n >= N_NODES) return;
    int lo = off[n], hi = off[n+1];
    float inv = 1.f / fmaxf((float)(hi - lo), 1.f);

    float s0 = 0.f, s1 = 0.f;
    int r = lo;
    for (; r + 2 <= hi; r += 2) {
        s0 += msg_buf[(size_t)r * HID_C + o];
        s1 += msg_buf[(size_t)(r+1) * HID_C + o];
    }
    if (r < hi) s0 += msg_buf[(size_t)r * HID_C + o];
    float s = s0 + s1;

    float acc = fmaf(s, inv, bias[o]);
    const float* xr = xin + (size_t)n * IN_C;
    #pragma unroll
    for (int i = 0; i < IN_C; ++i)
        acc = fmaf(xr[i], root[i*HID_C+o], acc);
    xout[(size_t)n*HID_C + o] = acc > 0.f ? acc : (expf(acc) - 1.f);
}

// fused: global mean pool (batch sorted -> contiguous segments) + final linear
__global__ __launch_bounds__(64) void pool_final_kernel(
    const float* __restrict__ xin, const int* __restrict__ goff,
    const float* __restrict__ fcW, const float* __restrict__ fcb,
    float* __restrict__ out)
{
    __shared__ float part[4][HID_C];
    __shared__ float pooled[HID_C];
    int g = blockIdx.x;
    int t = threadIdx.x;
    int c = t & 15, sub = t >> 4;
    int lo = goff[g], hi = goff[g+1];
    float s = 0.f;
    for (int n = lo + sub; n < hi; n += 4)
        s += xin[(size_t)n*HID_C + c];
    part[sub][c] = s;
    __syncthreads();
    if (t < HID_C) {
        float v = (part[0][t] + part[1][t] + part[2][t] + part[3][t])
                  / fmaxf((float)(hi - lo), 1.f);
        pooled[t] = v;
    }
    __syncthreads();
    if (t < OUT_C) {
        float acc = fcb[t];
        #pragma unroll
        for (int i = 0; i < HID_C; ++i)
            acc = fmaf(pooled[i], fcW[i*OUT_C+t], acc);
        out[g*OUT_C + t] = acc;
    }
}

// ---------------- launch ----------------

extern "C" void kernel_launch(void* const* d_in, const int* in_sizes, int n_in,
                              void* d_out, int out_size, void* d_ws, size_t ws_size,
                              hipStream_t stream)
{
    const float* x     = (const float*)d_in[0];
    const int*   ei    = (const int*)d_in[1];
    const float* eattr = (const float*)d_in[2];
    const int*   batch = (const int*)d_in[3];
    const float* W1a   = (const float*)d_in[4];
    const float* b1a   = (const float*)d_in[5];
    const float* g1    = (const float*)d_in[6];
    const float* bt1   = (const float*)d_in[7];
    const float* m1    = (const float*)d_in[8];
    const float* v1    = (const float*)d_in[9];
    const float* W1b   = (const float*)d_in[10];
    const float* b1b   = (const float*)d_in[11];
    const float* root1 = (const float*)d_in[12];
    const float* bias1 = (const float*)d_in[13];
    const float* W2a   = (const float*)d_in[14];
    const float* b2a   = (const float*)d_in[15];
    const float* g2    = (const float*)d_in[16];
    const float* bt2   = (const float*)d_in[17];
    const float* m2    = (const float*)d_in[18];
    const float* v2    = (const float*)d_in[19];
    const float* W2b   = (const float*)d_in[20];
    const float* b2b   = (const float*)d_in[21];
    const float* root2 = (const float*)d_in[22];
    const float* bias2 = (const float*)d_in[23];
    const float* fcW   = (const float*)d_in[24];
    const float* fcb   = (const float*)d_in[25];

    const int* src = ei;
    const int* dst = ei + N_EDGES;

    float* ws   = (float*)d_ws;
    float* MSG  = ws;                          // 12,800,000 f
    float* X1   = ws + 12800000;               //    800,000 f
    float* X2   = ws + 13600000;               //    800,000 f
    int*   DEGI = (int*)(ws + 14400000);       //     50,000 i
    int*   OFF  = (int*)(ws + 14450000);       //     50,001 i (+pad)
    int*   CUR1 = (int*)(ws + 14500096);       //    200,000 i (stride-4)
    int*   CUR2 = (int*)(ws + 14700096);       //    200,000 i (stride-4)
    int*   GOFF = (int*)(ws + 14900096);       //        501 i (+pad)
    float* AC1  = ws + 14900608;               //        128 f
    float* AC2  = ws + 14900736;               //        128 f
    // total 14,900,864 f = 59.6 MB  (R2 used 61.4 MB successfully)

    hipMemsetAsync(DEGI, 0, N_NODES * sizeof(int), stream);
    prep_graph_kernel<<<3, 256, 0, stream>>>(W1a, b1a, g1, bt1, m1, v1,
                                             W2a, b2a, g2, bt2, m2, v2,
                                             batch, AC1, AC2, GOFF);
    hist_kernel<<<N_EDGES/256, 256, 0, stream>>>(dst, DEGI);
    scan_kernel<<<1, 1024, 0, stream>>>(DEGI, OFF, CUR1, CUR2);

    const int HALF = N_EDGES / 2;
    edge_kernel2<<<(HALF+255)/256, 256, 0, stream>>>(x, src, dst, eattr, CUR1,
                                                     AC1, W1b, b1b, MSG);
    node_gather_kernel<<<(N_NODES*16+255)/256, 256, 0, stream>>>(x, MSG, OFF,
                                                                 root1, bias1, X1);

    edge_kernel2<<<(HALF+255)/256, 256, 0, stream>>>(X1, src, dst, eattr, CUR2,
                                                     AC2, W2b, b2b, MSG);
    node_gather_kernel<<<(N_NODES*16+255)/256, 256, 0, stream>>>(X1, MSG, OFF,
                                                                 root2, bias2, X2);

    pool_final_kernel<<<N_GRAPHS, 64, 0, stream>>>(X2, GOFF, fcW, fcb, (float*)d_out);
}